// Round 5
// baseline (1146.715 us; speedup 1.0000x reference)
//
#include <hip/hip_runtime.h>
#include <math.h>

// Sizes fixed by the reference: B=512, T=1024, D_IN=D_OUT=64, H=256.
#define HDIM 256
#define DDIM 64
#define BROWS 512
#define TSTEPS 1024
// Augmented rows: 65 weight rows (t-row + 64 state rows) + 1 bias row.
#define AROWS 66

// ---- Setup: compose the linear MLP into one 66x64 affine map ----
__global__ void compose1(const float* __restrict__ W0, const float* __restrict__ b0,
                         const float* __restrict__ W1, const float* __restrict__ b1,
                         float* __restrict__ out1) {
    int r = blockIdx.x;    // 0..65
    int c = threadIdx.x;   // 0..255
    const float* arow = (r < 65) ? (W0 + r * HDIM) : b0;
    float acc = (r == 65) ? b1[c] : 0.0f;
    for (int h = 0; h < HDIM; ++h)
        acc = fmaf(arow[h], W1[h * HDIM + c], acc);
    out1[r * HDIM + c] = acc;
}

__global__ void compose2(const float* __restrict__ in1,
                         const float* __restrict__ W2, const float* __restrict__ b2,
                         float* __restrict__ out2) {
    int r = blockIdx.x, c = threadIdx.x;
    const float* arow = in1 + r * HDIM;
    float acc = (r == 65) ? b2[c] : 0.0f;
    for (int h = 0; h < HDIM; ++h)
        acc = fmaf(arow[h], W2[h * HDIM + c], acc);
    out2[r * HDIM + c] = acc;
}

__global__ void compose3(const float* __restrict__ in2,
                         const float* __restrict__ W3, const float* __restrict__ b3,
                         float* __restrict__ out3) {
    int r = blockIdx.x, c = threadIdx.x;   // c 0..63
    const float* arow = in2 + r * HDIM;
    float acc = (r == 65) ? b3[c] : 0.0f;
    for (int h = 0; h < HDIM; ++h)
        acc = fmaf(arow[h], W3[h * DDIM + c], acc);
    out3[r * DDIM + c] = acc;
}

// ---- Main scan: one wave per TWO batch rows, lane = output dim ----
// y_new[d] = y[d] + factor_k * tanh(b_eff[d] + t_k*w_t[d] + sum_j y[j]*Weff[j][d])
//
// Round-4 lesson: with 1 wave/SIMD every dependent gap (TRANS latency,
// readlane->SGPR hazards, waitcnt) is raw stall — removing DS ops only
// bought 47 of ~720 cyc/step. So give the wave a second independent row:
// row B's instructions fill row A's stalls. LDS same-address float4
// broadcasts (conflict-free, DS pipe) replace the 128-instr readlane
// stream; the DS pipe runs concurrently with the FMA stream. The t-term
// fma(t_k, wt, bias) is shared by both rows. No barriers (single-wave
// block, in-order DS); no global loads in the loop.
__launch_bounds__(64)
__global__ void fode_scan(const float* __restrict__ x, const float* __restrict__ t,
                          const float* __restrict__ Weff,   // 66 x 64 composed
                          float* __restrict__ out) {
    const int bA = blockIdx.x * 2;      // rows bA, bA+1
    const int d  = threadIdx.x;         // 0..63

    __shared__ float  yAl[DDIM];
    __shared__ float  yBl[DDIM];
    __shared__ float2 plds[TSTEPS];   // (t_k, factor_k); entry TSTEPS-1 unused

    const float invG = 0.56418958354775628695f;  // 1/Gamma(0.5)

    // Stage per-step params: coalesced, once per block (t is 4 KB, L2-hot).
    for (int i = d; i < TSTEPS - 1; i += DDIM) {
        float t0 = t[i];
        float t1 = t[i + 1];
        plds[i] = make_float2(t0, sqrtf(t1 - t0) * invG);
    }

    // Weff column for this lane: W[j] = Weff[(1+j)*64 + d]
    float W[DDIM];
#pragma unroll
    for (int j = 0; j < DDIM; ++j)
        W[j] = Weff[(1 + j) * DDIM + d];
    const float wt   = Weff[d];                 // t-coefficient row
    const float bias = Weff[65 * DDIM + d];     // folded bias row

    float ya = x[bA * DDIM + d];
    float yb = x[(bA + 1) * DDIM + d];
    float* opA = out + (size_t)bA * TSTEPS * DDIM + d;
    float* opB = opA + (size_t)TSTEPS * DDIM;
    *opA = ya;                                   // solution[:,0,:] = x
    *opB = yb;
    yAl[d] = ya;
    yBl[d] = yb;
    asm volatile("" ::: "memory");               // compiler fence (1-wave block)

    float2 prm = plds[0];                        // same-wave DS: in-order

    for (int k = 0; k < TSTEPS - 1; ++k) {
        float2 prm_next = plds[k + 1];           // prefetch; garbage at last iter, unused

        float base = fmaf(prm.x, wt, bias);      // shared by both rows
        float aA0 = base, aA1 = 0.f, aA2 = 0.f, aA3 = 0.f;
        float aB0 = base, aB1 = 0.f, aB2 = 0.f, aB3 = 0.f;
#pragma unroll
        for (int c = 0; c < 16; ++c) {
            float4 va = *reinterpret_cast<const float4*>(&yAl[c * 4]);
            float4 vb = *reinterpret_cast<const float4*>(&yBl[c * 4]);
            aA0 = fmaf(va.x, W[c * 4 + 0], aA0);
            aB0 = fmaf(vb.x, W[c * 4 + 0], aB0);
            aA1 = fmaf(va.y, W[c * 4 + 1], aA1);
            aB1 = fmaf(vb.y, W[c * 4 + 1], aB1);
            aA2 = fmaf(va.z, W[c * 4 + 2], aA2);
            aB2 = fmaf(vb.z, W[c * 4 + 2], aB2);
            aA3 = fmaf(va.w, W[c * 4 + 3], aA3);
            aB3 = fmaf(vb.w, W[c * 4 + 3], aB3);
        }
        float sA = (aA0 + aA1) + (aA2 + aA3);
        float sB = (aB0 + aB1) + (aB2 + aB3);

        // tanh(s) = 1 - 2/(exp(2s)+1), via raw v_exp_f32 + v_rcp_f32;
        // the two rows' TRANS chains interleave.
        float eA  = __builtin_amdgcn_exp2f(sA * 2.88539008177792681472f); // 2*log2(e)
        float eB  = __builtin_amdgcn_exp2f(sB * 2.88539008177792681472f);
        float thA = fmaf(-2.0f, __builtin_amdgcn_rcpf(eA + 1.0f), 1.0f);
        float thB = fmaf(-2.0f, __builtin_amdgcn_rcpf(eB + 1.0f), 1.0f);

        ya = fmaf(prm.y, thA, ya);
        yb = fmaf(prm.y, thB, yb);

        asm volatile("" ::: "memory");
        yAl[d] = ya;                              // next iter's input (in-order DS)
        yBl[d] = yb;
        opA += DDIM;
        opB += DDIM;
        *opA = ya;                                // fire-and-forget, never waited
        *opB = yb;
        asm volatile("" ::: "memory");
        prm = prm_next;
    }
}

extern "C" void kernel_launch(void* const* d_in, const int* in_sizes, int n_in,
                              void* d_out, int out_size, void* d_ws, size_t ws_size,
                              hipStream_t stream) {
    const float* x  = (const float*)d_in[0];
    const float* t  = (const float*)d_in[1];
    const float* W0 = (const float*)d_in[2];
    const float* b0 = (const float*)d_in[3];
    const float* W1 = (const float*)d_in[4];
    const float* b1 = (const float*)d_in[5];
    const float* W2 = (const float*)d_in[6];
    const float* b2 = (const float*)d_in[7];
    const float* W3 = (const float*)d_in[8];
    const float* b3 = (const float*)d_in[9];
    float* out = (float*)d_out;

    float* buf1 = (float*)d_ws;            // 66*256 floats
    float* buf2 = buf1 + AROWS * HDIM;     // 66*256 floats
    float* buf3 = buf2 + AROWS * HDIM;     // 66*64 floats

    compose1<<<AROWS, HDIM, 0, stream>>>(W0, b0, W1, b1, buf1);
    compose2<<<AROWS, HDIM, 0, stream>>>(buf1, W2, b2, buf2);
    compose3<<<AROWS, DDIM, 0, stream>>>(buf2, W3, b3, buf3);
    fode_scan<<<BROWS / 2, DDIM, 0, stream>>>(x, t, buf3, out);
}

// Round 6
// 334.291 us; speedup vs baseline: 3.4303x; 3.4303x over previous
//
#include <hip/hip_runtime.h>
#include <math.h>

// Sizes fixed by the reference: B=512, T=1024, D_IN=D_OUT=64, H=256.
#define HDIM 256
#define DDIM 64
#define BROWS 512
#define TSTEPS 1024
// Augmented rows: 65 weight rows (t-row + 64 state rows) + 1 bias row.
#define AROWS 66

// ---- Setup: compose the linear MLP into one 66x64 affine map ----
__global__ void compose1(const float* __restrict__ W0, const float* __restrict__ b0,
                         const float* __restrict__ W1, const float* __restrict__ b1,
                         float* __restrict__ out1) {
    int r = blockIdx.x;    // 0..65
    int c = threadIdx.x;   // 0..255
    const float* arow = (r < 65) ? (W0 + r * HDIM) : b0;
    float acc = (r == 65) ? b1[c] : 0.0f;
    for (int h = 0; h < HDIM; ++h)
        acc = fmaf(arow[h], W1[h * HDIM + c], acc);
    out1[r * HDIM + c] = acc;
}

__global__ void compose2(const float* __restrict__ in1,
                         const float* __restrict__ W2, const float* __restrict__ b2,
                         float* __restrict__ out2) {
    int r = blockIdx.x, c = threadIdx.x;
    const float* arow = in1 + r * HDIM;
    float acc = (r == 65) ? b2[c] : 0.0f;
    for (int h = 0; h < HDIM; ++h)
        acc = fmaf(arow[h], W2[h * HDIM + c], acc);
    out2[r * HDIM + c] = acc;
}

__global__ void compose3(const float* __restrict__ in2,
                         const float* __restrict__ W3, const float* __restrict__ b3,
                         float* __restrict__ out3) {
    int r = blockIdx.x, c = threadIdx.x;   // c 0..63
    const float* arow = in2 + r * HDIM;
    float acc = (r == 65) ? b3[c] : 0.0f;
    for (int h = 0; h < HDIM; ++h)
        acc = fmaf(arow[h], W3[h * DDIM + c], acc);
    out3[r * DDIM + c] = acc;
}

// Broadcast y from lane j to all lanes via v_readlane (register file, no LDS).
__device__ __forceinline__ float bcast(float v, int lane) {
    return __uint_as_float(__builtin_amdgcn_readlane(__float_as_uint(v), lane));
}

// ---- Main scan: one wave per batch row, lane = output dim ----
// y_new[d] = y[d] + factor_k * tanh(b_eff[d] + t_k*w_t[d] + sum_j y[j]*Weff[j][d])
//
// Wall time = one wave's serial chain x 1023 steps (occupancy is irrelevant;
// round 5 proved adding rows per wave only lengthens the chain). Chain
// shortening here:
//  - hybrid broadcast: j=0..31 via v_readlane (VALU, no memory latency);
//    j=32..63 via 8 ds_read_b128 issued at the TOP of the iteration so
//    their ~120cyc LDS latency hides under the readlane+FMA stream.
//  - __launch_bounds__(64,1): full register budget, so W[64] stays in
//    arch VGPRs instead of AGPRs (r4/r5 showed VGPR_Count=44 => compiler
//    was paying one v_accvgpr_read per FMA).
//  - loop has NO global loads (params staged in LDS, prefetched), one
//    fire-and-forget store, one compiler fence.
__launch_bounds__(64, 1)
__global__ void fode_scan(const float* __restrict__ x, const float* __restrict__ t,
                          const float* __restrict__ Weff,   // 66 x 64 composed
                          float* __restrict__ out) {
    const int b = blockIdx.x;
    const int d = threadIdx.x;   // 0..63

    __shared__ float  ylds[DDIM];
    __shared__ float2 plds[TSTEPS];   // (t_k, factor_k); entry TSTEPS-1 unused

    const float invG = 0.56418958354775628695f;  // 1/Gamma(0.5)

    // Stage per-step params: coalesced, once per block (t is 4 KB, L2-hot).
    for (int i = d; i < TSTEPS - 1; i += DDIM) {
        float t0 = t[i];
        float t1 = t[i + 1];
        plds[i] = make_float2(t0, sqrtf(t1 - t0) * invG);
    }

    // Weff column for this lane: W[j] = Weff[(1+j)*64 + d]
    float W[DDIM];
#pragma unroll
    for (int j = 0; j < DDIM; ++j)
        W[j] = Weff[(1 + j) * DDIM + d];
    const float wt   = Weff[d];                 // t-coefficient row
    const float bias = Weff[65 * DDIM + d];     // folded bias row

    float y = x[b * DDIM + d];
    float* op = out + (size_t)b * TSTEPS * DDIM + d;
    *op = y;                                     // solution[:,0,:] = x
    ylds[d] = y;
    asm volatile("" ::: "memory");               // fence: write visible to reads

    float2 prm = plds[0];                        // same-wave DS: in-order

    for (int k = 0; k < TSTEPS - 1; ++k) {
        // Issue the upper-half broadcast reads FIRST; latency hides under
        // the readlane half below (no use until after it).
        float4 yv[8];
#pragma unroll
        for (int c = 0; c < 8; ++c)
            yv[c] = *reinterpret_cast<const float4*>(&ylds[32 + c * 4]);

        float2 prm_next = plds[k + 1];           // prefetch; garbage at last iter, unused

        float a0 = fmaf(prm.x, wt, bias), a1 = 0.f, a2 = 0.f, a3 = 0.f;
        // Lower half: register-file broadcast, zero memory latency.
#pragma unroll
        for (int j = 0; j < 32; j += 4) {
            a0 = fmaf(bcast(y, j + 0), W[j + 0], a0);
            a1 = fmaf(bcast(y, j + 1), W[j + 1], a1);
            a2 = fmaf(bcast(y, j + 2), W[j + 2], a2);
            a3 = fmaf(bcast(y, j + 3), W[j + 3], a3);
        }
        // Upper half: consume the LDS reads (returned by now).
#pragma unroll
        for (int c = 0; c < 8; ++c) {
            a0 = fmaf(yv[c].x, W[32 + c * 4 + 0], a0);
            a1 = fmaf(yv[c].y, W[32 + c * 4 + 1], a1);
            a2 = fmaf(yv[c].z, W[32 + c * 4 + 2], a2);
            a3 = fmaf(yv[c].w, W[32 + c * 4 + 3], a3);
        }
        float s = (a0 + a1) + (a2 + a3);

        // tanh(s) = 1 - 2/(exp(2s)+1), via raw v_exp_f32 + v_rcp_f32
        float e  = __builtin_amdgcn_exp2f(s * 2.88539008177792681472f); // 2*log2(e)
        float th = fmaf(-2.0f, __builtin_amdgcn_rcpf(e + 1.0f), 1.0f);

        y = fmaf(prm.y, th, y);

        ylds[d] = y;                              // next iter's input (in-order DS)
        asm volatile("" ::: "memory");            // fence before next iter's reads
        op += DDIM;
        *op = y;                                  // fire-and-forget, never waited
        prm = prm_next;
    }
}

extern "C" void kernel_launch(void* const* d_in, const int* in_sizes, int n_in,
                              void* d_out, int out_size, void* d_ws, size_t ws_size,
                              hipStream_t stream) {
    const float* x  = (const float*)d_in[0];
    const float* t  = (const float*)d_in[1];
    const float* W0 = (const float*)d_in[2];
    const float* b0 = (const float*)d_in[3];
    const float* W1 = (const float*)d_in[4];
    const float* b1 = (const float*)d_in[5];
    const float* W2 = (const float*)d_in[6];
    const float* b2 = (const float*)d_in[7];
    const float* W3 = (const float*)d_in[8];
    const float* b3 = (const float*)d_in[9];
    float* out = (float*)d_out;

    float* buf1 = (float*)d_ws;            // 66*256 floats
    float* buf2 = buf1 + AROWS * HDIM;     // 66*256 floats
    float* buf3 = buf2 + AROWS * HDIM;     // 66*64 floats

    compose1<<<AROWS, HDIM, 0, stream>>>(W0, b0, W1, b1, buf1);
    compose2<<<AROWS, HDIM, 0, stream>>>(buf1, W2, b2, buf2);
    compose3<<<AROWS, DDIM, 0, stream>>>(buf2, W3, b3, buf3);
    fode_scan<<<BROWS, DDIM, 0, stream>>>(x, t, buf3, out);
}

// Round 7
// 286.219 us; speedup vs baseline: 4.0064x; 1.1680x over previous
//
#include <hip/hip_runtime.h>
#include <math.h>

// Sizes fixed by the reference: B=512, T=1024, D_IN=D_OUT=64, H=256.
#define HDIM 256
#define DDIM 64
#define BROWS 512
#define TSTEPS 1024
// Augmented rows: 65 weight rows (t-row + 64 state rows) + 1 bias row.
#define AROWS 66

typedef float f32x2 __attribute__((ext_vector_type(2)));
typedef float f32x4 __attribute__((ext_vector_type(4)));

// ---- Setup: compose the linear MLP into one 66x64 affine map ----
__global__ void compose1(const float* __restrict__ W0, const float* __restrict__ b0,
                         const float* __restrict__ W1, const float* __restrict__ b1,
                         float* __restrict__ out1) {
    int r = blockIdx.x;    // 0..65
    int c = threadIdx.x;   // 0..255
    const float* arow = (r < 65) ? (W0 + r * HDIM) : b0;
    float acc = (r == 65) ? b1[c] : 0.0f;
    for (int h = 0; h < HDIM; ++h)
        acc = fmaf(arow[h], W1[h * HDIM + c], acc);
    out1[r * HDIM + c] = acc;
}

__global__ void compose2(const float* __restrict__ in1,
                         const float* __restrict__ W2, const float* __restrict__ b2,
                         float* __restrict__ out2) {
    int r = blockIdx.x, c = threadIdx.x;
    const float* arow = in1 + r * HDIM;
    float acc = (r == 65) ? b2[c] : 0.0f;
    for (int h = 0; h < HDIM; ++h)
        acc = fmaf(arow[h], W2[h * HDIM + c], acc);
    out2[r * HDIM + c] = acc;
}

__global__ void compose3(const float* __restrict__ in2,
                         const float* __restrict__ W3, const float* __restrict__ b3,
                         float* __restrict__ out3) {
    int r = blockIdx.x, c = threadIdx.x;   // c 0..63
    const float* arow = in2 + r * HDIM;
    float acc = (r == 65) ? b3[c] : 0.0f;
    for (int h = 0; h < HDIM; ++h)
        acc = fmaf(arow[h], W3[h * DDIM + c], acc);
    out3[r * DDIM + c] = acc;
}

// Packed 2xf32 FMA: acc.lo += a.lo*b.lo; acc.hi += a.hi*b.hi  (VOP3P, CDNA)
__device__ __forceinline__ void pkfma(f32x2& acc, f32x2 a, f32x2 b) {
    asm("v_pk_fma_f32 %0, %1, %2, %0" : "+v"(acc) : "v"(a), "v"(b));
}

// ---- Main scan: one wave per batch row, lane = output dim ----
// y_new[d] = y[d] + factor_k * tanh(b_eff[d] + t_k*w_t[d] + sum_j y[j]*Weff[j][d])
//
// Rounds 3-6 established: wall = per-step chain INSTRUCTION COUNT x ~5 cyc
// (lone-wave issue cadence) + exposed LDS turnaround + TRANS tail. So the
// lever is instruction count. v_pk_fma_f32 (packed 2xf32, VOP3P) halves
// the dot: 32 pk_fma over j-pairs, with W pre-split into per-lane VGPR
// pairs Wp[c] = (W[2c][d], W[2c+1][d]) and y-pairs coming straight out of
// 16 ds_read_b128 broadcasts (no extraction cost: b128 lands in 4
// consecutive VGPRs = 2 ready pairs). Chain ~64 instrs vs 115 in r6.
__launch_bounds__(64, 1)
__global__ void fode_scan(const float* __restrict__ x, const float* __restrict__ t,
                          const float* __restrict__ Weff,   // 66 x 64 composed
                          float* __restrict__ out) {
    const int b = blockIdx.x;
    const int d = threadIdx.x;   // 0..63

    __shared__ float  ylds[DDIM];
    __shared__ float2 plds[TSTEPS];   // (t_k, factor_k); entry TSTEPS-1 unused

    const float invG = 0.56418958354775628695f;  // 1/Gamma(0.5)

    // Stage per-step params: coalesced, once per block (t is 4 KB, L2-hot).
    for (int i = d; i < TSTEPS - 1; i += DDIM) {
        float t0 = t[i];
        float t1 = t[i + 1];
        plds[i] = make_float2(t0, sqrtf(t1 - t0) * invG);
    }

    // W column for this lane, as j-pairs: Wp[c] = (W[2c][d], W[2c+1][d])
    f32x2 Wp[DDIM / 2];
#pragma unroll
    for (int c = 0; c < DDIM / 2; ++c) {
        Wp[c].x = Weff[(1 + 2 * c) * DDIM + d];
        Wp[c].y = Weff[(2 + 2 * c) * DDIM + d];
    }
    const float wt   = Weff[d];                 // t-coefficient row
    const float bias = Weff[65 * DDIM + d];     // folded bias row

    float y = x[b * DDIM + d];
    float* op = out + (size_t)b * TSTEPS * DDIM + d;
    *op = y;                                     // solution[:,0,:] = x
    ylds[d] = y;
    asm volatile("" ::: "memory");               // fence: write visible to reads

    float2 prm = plds[0];                        // same-wave DS: in-order

    for (int k = 0; k < TSTEPS - 1; ++k) {
        // Issue all 16 broadcast reads up front (same-address = conflict-free);
        // consumption below uses counted lgkmcnt waits.
        f32x4 yv[16];
#pragma unroll
        for (int c = 0; c < 16; ++c)
            yv[c] = *reinterpret_cast<const f32x4*>(&ylds[c * 4]);

        float2 prm_next = plds[k + 1];           // prefetch; garbage at last iter, unused
        float base = fmaf(prm.x, wt, bias);      // t-term + bias

        f32x2 acc0 = {0.f, 0.f}, acc1 = {0.f, 0.f};
#pragma unroll
        for (int c = 0; c < 16; ++c) {
            f32x2 lo = __builtin_shufflevector(yv[c], yv[c], 0, 1);
            f32x2 hi = __builtin_shufflevector(yv[c], yv[c], 2, 3);
            pkfma(acc0, lo, Wp[2 * c + 0]);
            pkfma(acc1, hi, Wp[2 * c + 1]);
        }
        float s = ((acc0.x + acc0.y) + (acc1.x + acc1.y)) + base;

        // tanh(s) = 1 - 2/(exp(2s)+1), via raw v_exp_f32 + v_rcp_f32
        float e  = __builtin_amdgcn_exp2f(s * 2.88539008177792681472f); // 2*log2(e)
        float th = fmaf(-2.0f, __builtin_amdgcn_rcpf(e + 1.0f), 1.0f);

        y = fmaf(prm.y, th, y);

        ylds[d] = y;                              // next iter's input (in-order DS)
        asm volatile("" ::: "memory");            // fence before next iter's reads
        op += DDIM;
        *op = y;                                  // fire-and-forget, never waited
        prm = prm_next;
    }
}

extern "C" void kernel_launch(void* const* d_in, const int* in_sizes, int n_in,
                              void* d_out, int out_size, void* d_ws, size_t ws_size,
                              hipStream_t stream) {
    const float* x  = (const float*)d_in[0];
    const float* t  = (const float*)d_in[1];
    const float* W0 = (const float*)d_in[2];
    const float* b0 = (const float*)d_in[3];
    const float* W1 = (const float*)d_in[4];
    const float* b1 = (const float*)d_in[5];
    const float* W2 = (const float*)d_in[6];
    const float* b2 = (const float*)d_in[7];
    const float* W3 = (const float*)d_in[8];
    const float* b3 = (const float*)d_in[9];
    float* out = (float*)d_out;

    float* buf1 = (float*)d_ws;            // 66*256 floats
    float* buf2 = buf1 + AROWS * HDIM;     // 66*256 floats
    float* buf3 = buf2 + AROWS * HDIM;     // 66*64 floats

    compose1<<<AROWS, HDIM, 0, stream>>>(W0, b0, W1, b1, buf1);
    compose2<<<AROWS, HDIM, 0, stream>>>(buf1, W2, b2, buf2);
    compose3<<<AROWS, DDIM, 0, stream>>>(buf2, W3, b3, buf3);
    fode_scan<<<BROWS, DDIM, 0, stream>>>(x, t, buf3, out);
}